// Round 1
// 4720.255 us; speedup vs baseline: 1.0553x; 1.0553x over previous
//
#include <hip/hip_runtime.h>
#include <hip/hip_bf16.h>
#include <math.h>

typedef unsigned short u16;
typedef unsigned int u32;
typedef __attribute__((ext_vector_type(8))) short short8;
typedef __attribute__((ext_vector_type(4))) float float4v;

#define DEV __device__ __forceinline__

DEV u16 f2bf(float x) {
    __hip_bfloat16 h = __float2bfloat16(x);
    return *reinterpret_cast<u16*>(&h);
}

// ---------------------------------------------------------------------------
// Embedding: h[t,:] = bpe[x[t],:] + pe[t%128,:]  (writes f32 + bf16 copies)
// ---------------------------------------------------------------------------
__global__ __launch_bounds__(256) void embed_k(const int* __restrict__ x,
                                               const float* __restrict__ bpe,
                                               const float* __restrict__ pe,
                                               float* __restrict__ hf, u16* __restrict__ hb) {
    long trow = blockIdx.x;
    int s = (int)(trow & 127);
    long tok = x[trow];
    int t = threadIdx.x;
#pragma unroll
    for (int kk = 0; kk < 3; kk++) {
        int j = t + kk * 256;
        float v = bpe[tok * 768 + j] + pe[(long)s * 768 + j];
        hf[trow * 768 + j] = v;
        hb[trow * 768 + j] = f2bf(v);
    }
}

// ---------------------------------------------------------------------------
// LayerNorm over rows of 768: out f32 + bf16
// ---------------------------------------------------------------------------
__global__ __launch_bounds__(256) void layernorm_k(const float* __restrict__ in,
                                                   const float* __restrict__ w,
                                                   const float* __restrict__ bb,
                                                   float* __restrict__ hf, u16* __restrict__ hb) {
    long trow = blockIdx.x;
    const float* xp = in + trow * 768;
    int t = threadIdx.x;
    float v[3];
    float s = 0.f, sq = 0.f;
#pragma unroll
    for (int kk = 0; kk < 3; kk++) {
        v[kk] = xp[t + kk * 256];
        s += v[kk];
        sq += v[kk] * v[kk];
    }
#pragma unroll
    for (int off = 32; off; off >>= 1) {
        s += __shfl_xor(s, off);
        sq += __shfl_xor(sq, off);
    }
    __shared__ float rs[4], rq[4];
    int wave = t >> 6, lane = t & 63;
    if (lane == 0) { rs[wave] = s; rq[wave] = sq; }
    __syncthreads();
    s = rs[0] + rs[1] + rs[2] + rs[3];
    sq = rq[0] + rq[1] + rq[2] + rq[3];
    float mu = s * (1.f / 768.f);
    float var = sq * (1.f / 768.f) - mu * mu;
    float rstd = rsqrtf(var + 1e-5f);
#pragma unroll
    for (int kk = 0; kk < 3; kk++) {
        int j = t + kk * 256;
        float y = (v[kk] - mu) * rstd * w[j] + bb[j];
        hf[trow * 768 + j] = y;
        hb[trow * 768 + j] = f2bf(y);
    }
}

// ---------------------------------------------------------------------------
// Transpose + f32->bf16 convert: dst[c][r] = src[r][c], zero-pad rows c in [C,Cpad)
// z = layer*zmod + sub:  src += l*src_lstride + sub*src_zstride
//                        dst += l*dst_lstride + sub*dst_zstride
// (batches all 12 layers in one launch when hoisted)
// ---------------------------------------------------------------------------
__global__ __launch_bounds__(256) void transpose_cvt(const float* __restrict__ src,
                                                     u16* __restrict__ dst,
                                                     int R, int C, int src_ld, int dst_ld,
                                                     int Cpad,
                                                     size_t src_zstride, size_t dst_zstride,
                                                     int zmod,
                                                     size_t src_lstride, size_t dst_lstride) {
    __shared__ float tile[32][33];
    int z = blockIdx.z;
    int l = z / zmod, sub = z - l * zmod;
    src += (size_t)l * src_lstride + (size_t)sub * src_zstride;
    dst += (size_t)l * dst_lstride + (size_t)sub * dst_zstride;
    int tx = threadIdx.x & 31, ty = threadIdx.x >> 5;  // 32 x 8
    int r0 = blockIdx.y * 32, c0 = blockIdx.x * 32;
#pragma unroll
    for (int i = 0; i < 4; i++) {
        int r = r0 + ty + i * 8, c = c0 + tx;
        tile[ty + i * 8][tx] = (r < R && c < C) ? src[(size_t)r * src_ld + c] : 0.f;
    }
    __syncthreads();
#pragma unroll
    for (int i = 0; i < 4; i++) {
        int c = c0 + ty + i * 8, r = r0 + tx;
        if (c < Cpad && r < R) dst[(size_t)c * dst_ld + r] = f2bf(tile[tx][ty + i * 8]);
    }
}

// ---------------------------------------------------------------------------
// Pack QKV bias [768|768|768] -> qkvb[l][2304] for all 12 layers
// ---------------------------------------------------------------------------
__global__ void pack_qkv_bias(const float* __restrict__ bq, const float* __restrict__ bk,
                              const float* __restrict__ bv, float* __restrict__ qkvb) {
    int l = blockIdx.y;
    int j = blockIdx.x * 256 + threadIdx.x;
    if (j < 2304)
        qkvb[l * 2304 + j] =
            (j < 768) ? bq[l * 768 + j] : (j < 1536 ? bk[l * 768 + j - 768] : bv[l * 768 + j - 1536]);
}

// ---------------------------------------------------------------------------
// GEMM: C[M,N] = A[M,K](bf16,row-major) @ Bt[N,K](bf16,row-major)^T + bias
// 128x128 tile, BK=32, 256 threads (4 waves, each 64x64 via 4x4 mfma 16x16x32)
// 2-phase double-buffered main loop (T3-minimal): issue next-tile
// global_load_lds BEFORE ds_read+MFMA of current tile; one barrier per iter
// (__syncthreads == vmcnt(0)+lgkmcnt(0)+s_barrier, exactly the recipe's tail).
// EPI: 0 = store f32 (acc+bias)
//      1 = store f32 (acc+bias+res_in)            [attn out proj + residual]
//      2 = store bf16 (acc+bias)                  [FFN1 -> t1]
//      3 = store f32 (res_in + gelu(acc+bias))    [FFN2 + gelu + residual]
// NSW: 1 = M-fastest grid (gridDim.x = M-blocks) + bijective XCD-chunk
//      swizzle (all M-blocks of one B-panel co-located on one XCD) +
//      non-temporal C stores. Used for the vocab projection.
// ---------------------------------------------------------------------------
template <int EPI, int NSW>
__global__ __launch_bounds__(256) void gemm_bt(const u16* __restrict__ A,
                                               const u16* __restrict__ Bt,
                                               const float* __restrict__ bias,
                                               const float* __restrict__ res_in,
                                               float* __restrict__ outf, u16* __restrict__ outb,
                                               int M, int N, int K) {
    __shared__ __align__(16) u16 As[2 * 128 * 32];
    __shared__ __align__(16) u16 Bs[2 * 128 * 32];
    const int t = threadIdx.x;
    const int lane = t & 63, wave = t >> 6;
    const int ln15 = lane & 15, quad = lane >> 4;
    const int wm = (wave >> 1) * 64, wn = (wave & 1) * 64;

    long mb, nb;
    if constexpr (NSW) {
        int nwg = (int)(gridDim.x * gridDim.y);
        int bid = (int)(blockIdx.x + blockIdx.y * gridDim.x);
        int q = nwg >> 3, r = nwg & 7;
        int xcd = bid & 7, loc = bid >> 3;
        int swz = (xcd < r) ? xcd * (q + 1) + loc : r * (q + 1) + (xcd - r) * q + loc;
        mb = swz % (int)gridDim.x;  // gridDim.x = #M-blocks (fastest)
        nb = swz / (int)gridDim.x;
    } else {
        mb = blockIdx.y;
        nb = blockIdx.x;
    }
    const long m0 = mb * 128, n0 = nb * 128;

    auto stage = [&](int buf, int kb) {
        u16* asb = As + buf * (128 * 32);
        u16* bsb = Bs + buf * (128 * 32);
#pragma unroll
        for (int i = 0; i < 2; i++) {
            int li = i * 256 + t;
            const u16* ga = A + (m0 + (li >> 2)) * (long)K + kb + (li & 3) * 8;
            __builtin_amdgcn_global_load_lds(
                (const __attribute__((address_space(1))) u32*)ga,
                (__attribute__((address_space(3))) u32*)(asb + li * 8), 16, 0, 0);
            const u16* gb = Bt + (n0 + (li >> 2)) * (long)K + kb + (li & 3) * 8;
            __builtin_amdgcn_global_load_lds(
                (const __attribute__((address_space(1))) u32*)gb,
                (__attribute__((address_space(3))) u32*)(bsb + li * 8), 16, 0, 0);
        }
    };

    float4v acc[4][4];
#pragma unroll
    for (int i = 0; i < 4; i++)
#pragma unroll
        for (int j = 0; j < 4; j++) acc[i][j] = float4v{0.f, 0.f, 0.f, 0.f};

    stage(0, 0);
    __syncthreads();
    int cur = 0;
    for (int kb = 0; kb < K; kb += 32) {
        if (kb + 32 < K) stage(cur ^ 1, kb + 32);  // prefetch overlaps ds_read+MFMA below
        const u16* asb = As + cur * (128 * 32);
        const u16* bsb = Bs + cur * (128 * 32);
        short8 af[4], bfr[4];
#pragma unroll
        for (int ti = 0; ti < 4; ti++)
            af[ti] = *(const short8*)(asb + (wm + ti * 16 + ln15) * 32 + quad * 8);
#pragma unroll
        for (int tj = 0; tj < 4; tj++)
            bfr[tj] = *(const short8*)(bsb + (wn + tj * 16 + ln15) * 32 + quad * 8);
#pragma unroll
        for (int ti = 0; ti < 4; ti++)
#pragma unroll
            for (int tj = 0; tj < 4; tj++)
                acc[ti][tj] = __builtin_amdgcn_mfma_f32_16x16x32_bf16(af[ti], bfr[tj],
                                                                     acc[ti][tj], 0, 0, 0);
        __syncthreads();  // vmcnt(0): prefetch landed; barrier: buffers swappable
        cur ^= 1;
    }

#pragma unroll
    for (int ti = 0; ti < 4; ti++) {
#pragma unroll
        for (int r = 0; r < 4; r++) {
            long gm = m0 + wm + ti * 16 + quad * 4 + r;
#pragma unroll
            for (int tj = 0; tj < 4; tj++) {
                long gn = n0 + wn + tj * 16 + ln15;
                if (gn < N) {
                    float v = acc[ti][tj][r] + bias[gn];
                    if constexpr (EPI == 0) {
                        if constexpr (NSW)
                            __builtin_nontemporal_store(v, outf + gm * (long)N + gn);
                        else
                            outf[gm * (long)N + gn] = v;
                    } else if constexpr (EPI == 1) {
                        outf[gm * (long)N + gn] = v + res_in[gm * (long)N + gn];
                    } else if constexpr (EPI == 2) {
                        outb[gm * (long)N + gn] = f2bf(v);
                    } else {
                        float g = 0.5f * v * (1.f + erff(v * 0.70710678118654752f));
                        outf[gm * (long)N + gn] = res_in[gm * (long)N + gn] + g;
                    }
                }
            }
        }
    }
}

// ---------------------------------------------------------------------------
// Attention: one block per (b,h). S=128, HD=64. f32 math.
// qkv layout: [t=b*128+s][2304] with cols 0..767=Q, 768..1535=K, 1536..2303=V
// writes o (concat heads) as bf16 [t][768]
// ---------------------------------------------------------------------------
__global__ __launch_bounds__(256) void attn_k(const float* __restrict__ qkv,
                                              const int* __restrict__ ignore,
                                              u16* __restrict__ obf) {
    const int bh = blockIdx.x;
    const int b = bh / 12, h = bh % 12;
    __shared__ float ks[128][65];
    __shared__ float vs[128][64];
    __shared__ float qrow[4][64];
    __shared__ float ps[4][128];
    __shared__ int ig[128];
    const int t = threadIdx.x;
    for (int i = t; i < 128 * 64; i += 256) {
        int s = i >> 6, e = i & 63;
        size_t base = ((size_t)(b * 128 + s)) * 2304 + h * 64 + e;
        ks[s][e] = qkv[base + 768];
        vs[s][e] = qkv[base + 1536];
    }
    if (t < 128) ig[t] = ignore[b * 128 + t];
    __syncthreads();
    const int wave = t >> 6, lane = t & 63;
    for (int r = wave; r < 128; r += 4) {
        qrow[wave][lane] = qkv[((size_t)(b * 128 + r)) * 2304 + h * 64 + lane];
        float s1 = 0.f, s2 = 0.f;
#pragma unroll 8
        for (int e = 0; e < 64; e++) {
            float qe = qrow[wave][e];
            s1 = fmaf(qe, ks[lane][e], s1);
            s2 = fmaf(qe, ks[lane + 64][e], s2);
        }
        s1 *= 0.125f;  // 1/sqrt(64)
        s2 *= 0.125f;
        int k1 = lane, k2 = lane + 64;
        bool ok1 = (k1 <= r) && (ig[k1] == 0 || k1 == r);
        bool ok2 = (k2 <= r) && (ig[k2] == 0 || k2 == r);
        if (!ok1) s1 = -3.0e38f;
        if (!ok2) s2 = -3.0e38f;
        float mx = fmaxf(s1, s2);
#pragma unroll
        for (int off = 32; off; off >>= 1) mx = fmaxf(mx, __shfl_xor(mx, off));
        float e1 = expf(s1 - mx), e2 = expf(s2 - mx);
        float sm = e1 + e2;
#pragma unroll
        for (int off = 32; off; off >>= 1) sm += __shfl_xor(sm, off);
        float inv = 1.f / sm;
        ps[wave][k1] = e1 * inv;
        ps[wave][k2] = e2 * inv;
        float o = 0.f;
#pragma unroll 8
        for (int kp = 0; kp < 128; kp++) o = fmaf(ps[wave][kp], vs[kp][lane], o);
        obf[((size_t)(b * 128 + r)) * 768 + h * 64 + lane] = f2bf(o);
    }
}

// ---------------------------------------------------------------------------
extern "C" void kernel_launch(void* const* d_in, const int* in_sizes, int n_in,
                              void* d_out, int out_size, void* d_ws, size_t ws_size,
                              hipStream_t stream) {
    const int* x     = (const int*)d_in[0];
    const int* ign   = (const int*)d_in[1];
    const float* bpe = (const float*)d_in[2];
    const float* pe  = (const float*)d_in[3];
    const float* Wq  = (const float*)d_in[4];
    const float* bq  = (const float*)d_in[5];
    const float* Wk  = (const float*)d_in[6];
    const float* bk  = (const float*)d_in[7];
    const float* Wv  = (const float*)d_in[8];
    const float* bv  = (const float*)d_in[9];
    const float* Wo  = (const float*)d_in[10];
    const float* bo  = (const float*)d_in[11];
    const float* W1  = (const float*)d_in[12];
    const float* b1  = (const float*)d_in[13];
    const float* W2  = (const float*)d_in[14];
    const float* b2  = (const float*)d_in[15];
    const float* ln1w = (const float*)d_in[16];
    const float* ln1b = (const float*)d_in[17];
    const float* ln2w = (const float*)d_in[18];
    const float* ln2b = (const float*)d_in[19];
    const float* Wout = (const float*)d_in[20];
    const float* bout = (const float*)d_in[21];
    float* out = (float*)d_out;

    // Hoisted path needs 281,849,856 B of workspace; fall back to per-layer
    // weight staging (old behavior, ~126 MB) if the workspace is smaller.
    const bool hoist = ws_size >= 281849856ull;
    const int NL = hoist ? 12 : 1;

    char* p = (char*)d_ws;
    auto alloc = [&](size_t bytes) {
        char* r = p;
        p += (bytes + 255) & ~(size_t)255;
        return r;
    };
    float* hf   = (float*)alloc((size_t)2048 * 768 * 4);
    u16* hb     = (u16*)alloc((size_t)2048 * 768 * 2);
    float* res  = (float*)alloc((size_t)2048 * 768 * 4);
    float* qkv  = (float*)alloc((size_t)2048 * 2304 * 4);
    u16* obf    = (u16*)alloc((size_t)2048 * 768 * 2);
    u16* t1b    = (u16*)alloc((size_t)2048 * 3072 * 2);
    u16* Wqkv_t = (u16*)alloc((size_t)NL * 2304 * 768 * 2);
    u16* Wo_t   = (u16*)alloc((size_t)NL * 768 * 768 * 2);
    u16* W1_t   = (u16*)alloc((size_t)NL * 3072 * 768 * 2);
    u16* W2_t   = (u16*)alloc((size_t)NL * 768 * 3072 * 2);
    u16* Wout_t = (u16*)alloc((size_t)40064 * 768 * 2);
    float* qkvb = (float*)alloc((size_t)12 * 2304 * 4);

    embed_k<<<2048, 256, 0, stream>>>(x, bpe, pe, hf, hb);
    pack_qkv_bias<<<dim3(9, 12), 256, 0, stream>>>(bq, bk, bv, qkvb);
    // vocab weight repack [768 x 40000] -> [40064 x 768] bf16
    transpose_cvt<<<dim3(1252, 24, 1), 256, 0, stream>>>(Wout, Wout_t, 768, 40000, 40000, 768,
                                                         40064, 0, 0, 1, 0, 0);
    if (hoist) {
        // all 12 layers' weight repacks, batched into one launch each
        transpose_cvt<<<dim3(2, 24, 144), 256, 0, stream>>>(
            Wq, Wqkv_t, 768, 64, 64, 768, 64, (size_t)49152, (size_t)49152, 12,
            (size_t)589824, (size_t)1769472);
        transpose_cvt<<<dim3(2, 24, 144), 256, 0, stream>>>(
            Wk, Wqkv_t + 589824, 768, 64, 64, 768, 64, (size_t)49152, (size_t)49152, 12,
            (size_t)589824, (size_t)1769472);
        transpose_cvt<<<dim3(2, 24, 144), 256, 0, stream>>>(
            Wv, Wqkv_t + 1179648, 768, 64, 64, 768, 64, (size_t)49152, (size_t)49152, 12,
            (size_t)589824, (size_t)1769472);
        transpose_cvt<<<dim3(24, 24, 12), 256, 0, stream>>>(
            Wo, Wo_t, 768, 768, 768, 768, 768, 0, 0, 1, (size_t)589824, (size_t)589824);
        transpose_cvt<<<dim3(96, 24, 12), 256, 0, stream>>>(
            W1, W1_t, 768, 3072, 3072, 768, 3072, 0, 0, 1, (size_t)2359296, (size_t)2359296);
        transpose_cvt<<<dim3(24, 96, 12), 256, 0, stream>>>(
            W2, W2_t, 3072, 768, 768, 3072, 768, 0, 0, 1, (size_t)2359296, (size_t)2359296);
    }

    for (int l = 0; l < 12; l++) {
        const u16* WqkvL = Wqkv_t + (hoist ? (size_t)l * 1769472 : 0);
        const u16* WoL   = Wo_t   + (hoist ? (size_t)l * 589824 : 0);
        const u16* W1L   = W1_t   + (hoist ? (size_t)l * 2359296 : 0);
        const u16* W2L   = W2_t   + (hoist ? (size_t)l * 2359296 : 0);
        if (!hoist) {
            transpose_cvt<<<dim3(2, 24, 12), 256, 0, stream>>>(
                Wq + (size_t)l * 589824, Wqkv_t, 768, 64, 64, 768, 64,
                (size_t)49152, (size_t)49152, 12, 0, 0);
            transpose_cvt<<<dim3(2, 24, 12), 256, 0, stream>>>(
                Wk + (size_t)l * 589824, Wqkv_t + 589824, 768, 64, 64, 768, 64,
                (size_t)49152, (size_t)49152, 12, 0, 0);
            transpose_cvt<<<dim3(2, 24, 12), 256, 0, stream>>>(
                Wv + (size_t)l * 589824, Wqkv_t + 1179648, 768, 64, 64, 768, 64,
                (size_t)49152, (size_t)49152, 12, 0, 0);
            transpose_cvt<<<dim3(24, 24, 1), 256, 0, stream>>>(
                Wo + (size_t)l * 589824, Wo_t, 768, 768, 768, 768, 768, 0, 0, 1, 0, 0);
            transpose_cvt<<<dim3(96, 24, 1), 256, 0, stream>>>(
                W1 + (size_t)l * 2359296, W1_t, 768, 3072, 3072, 768, 3072, 0, 0, 1, 0, 0);
            transpose_cvt<<<dim3(24, 96, 1), 256, 0, stream>>>(
                W2 + (size_t)l * 2359296, W2_t, 3072, 768, 768, 3072, 768, 0, 0, 1, 0, 0);
        }
        // QKV GEMM -> qkv f32 [2048 x 2304]
        gemm_bt<0, 0><<<dim3(18, 16), 256, 0, stream>>>(hb, WqkvL, qkvb + l * 2304, nullptr,
                                                        qkv, nullptr, 2048, 2304, 768);
        // attention -> obf bf16 [2048 x 768]
        attn_k<<<192, 256, 0, stream>>>(qkv, ign, obf);
        // out proj + residual -> res f32
        gemm_bt<1, 0><<<dim3(6, 16), 256, 0, stream>>>(obf, WoL, bo + l * 768, hf, res,
                                                       nullptr, 2048, 768, 768);
        layernorm_k<<<2048, 256, 0, stream>>>(res, ln1w + l * 768, ln1b + l * 768, hf, hb);
        // FFN1 -> t1 bf16 [2048 x 3072]
        gemm_bt<2, 0><<<dim3(24, 16), 256, 0, stream>>>(hb, W1L, b1 + l * 3072, nullptr,
                                                        nullptr, t1b, 2048, 3072, 768);
        // FFN2 + gelu + residual -> res f32
        gemm_bt<3, 0><<<dim3(6, 16), 256, 0, stream>>>(t1b, W2L, b2 + l * 768, hf, res,
                                                       nullptr, 2048, 768, 3072);
        layernorm_k<<<2048, 256, 0, stream>>>(res, ln2w + l * 768, ln2b + l * 768, hf, hb);
    }

    // final vocab projection: out[2048 x 40000] f32
    // M-fastest grid + XCD-chunk swizzle + nt stores (NSW=1)
    gemm_bt<0, 1><<<dim3(16, 313), 256, 0, stream>>>(hb, Wout_t, bout, nullptr, out, nullptr,
                                                     2048, 40000, 768);
}

// Round 2
// 3720.027 us; speedup vs baseline: 1.3391x; 1.2689x over previous
//
#include <hip/hip_runtime.h>
#include <hip/hip_bf16.h>
#include <math.h>

typedef unsigned short u16;
typedef unsigned int u32;
typedef __attribute__((ext_vector_type(8))) short short8;
typedef __attribute__((ext_vector_type(4))) float float4v;

#define DEV __device__ __forceinline__

DEV u16 f2bf(float x) {
    __hip_bfloat16 h = __float2bfloat16(x);
    return *reinterpret_cast<u16*>(&h);
}

// ---------------------------------------------------------------------------
// Embedding: h[t,:] = bpe[x[t],:] + pe[t%128,:]  (writes f32 + bf16 copies)
// ---------------------------------------------------------------------------
__global__ __launch_bounds__(256) void embed_k(const int* __restrict__ x,
                                               const float* __restrict__ bpe,
                                               const float* __restrict__ pe,
                                               float* __restrict__ hf, u16* __restrict__ hb) {
    long trow = blockIdx.x;
    int s = (int)(trow & 127);
    long tok = x[trow];
    int t = threadIdx.x;
#pragma unroll
    for (int kk = 0; kk < 3; kk++) {
        int j = t + kk * 256;
        float v = bpe[tok * 768 + j] + pe[(long)s * 768 + j];
        hf[trow * 768 + j] = v;
        hb[trow * 768 + j] = f2bf(v);
    }
}

// ---------------------------------------------------------------------------
// Fused epilogue + LayerNorm:
//   t = sum_{p<NP} P[p][row] + bias;  if GELU: t = gelu(t)
//   h = resid[row] + t;  LN(h) -> hf (f32) + hb (bf16)
// P is stacked [NP][2048][768] f32 (split-K partials). Deterministic.
// ---------------------------------------------------------------------------
template <int NP, int GELU>
__global__ __launch_bounds__(256) void ln_fused_k(const float* __restrict__ P,
                                                  const float* __restrict__ bias,
                                                  const float* __restrict__ resid,
                                                  const float* __restrict__ w,
                                                  const float* __restrict__ bb,
                                                  float* __restrict__ hf, u16* __restrict__ hb) {
    const size_t PS = (size_t)2048 * 768;
    long trow = blockIdx.x;
    int t = threadIdx.x;
    float v[3];
    float s = 0.f, sq = 0.f;
#pragma unroll
    for (int kk = 0; kk < 3; kk++) {
        int j = t + kk * 256;
        size_t idx = trow * 768 + j;
        float a = P[idx];
        if constexpr (NP > 1) a += P[PS + idx];
        if constexpr (NP > 2) a += P[2 * PS + idx];
        a += bias[j];
        if constexpr (GELU) a = 0.5f * a * (1.f + erff(a * 0.70710678118654752f));
        float y = resid[idx] + a;
        v[kk] = y;
        s += y;
        sq += y * y;
    }
#pragma unroll
    for (int off = 32; off; off >>= 1) {
        s += __shfl_xor(s, off);
        sq += __shfl_xor(sq, off);
    }
    __shared__ float rs[4], rq[4];
    int wave = t >> 6, lane = t & 63;
    if (lane == 0) { rs[wave] = s; rq[wave] = sq; }
    __syncthreads();
    s = rs[0] + rs[1] + rs[2] + rs[3];
    sq = rq[0] + rq[1] + rq[2] + rq[3];
    float mu = s * (1.f / 768.f);
    float var = sq * (1.f / 768.f) - mu * mu;
    float rstd = rsqrtf(var + 1e-5f);
#pragma unroll
    for (int kk = 0; kk < 3; kk++) {
        int j = t + kk * 256;
        float y = (v[kk] - mu) * rstd * w[j] + bb[j];
        hf[trow * 768 + j] = y;
        hb[trow * 768 + j] = f2bf(y);
    }
}

// ---------------------------------------------------------------------------
// Transpose + f32->bf16 convert: dst[c][r] = src[r][c], zero-pad rows c in [C,Cpad)
// z = layer*zmod + sub:  src += l*src_lstride + sub*src_zstride
//                        dst += l*dst_lstride + sub*dst_zstride
// ---------------------------------------------------------------------------
__global__ __launch_bounds__(256) void transpose_cvt(const float* __restrict__ src,
                                                     u16* __restrict__ dst,
                                                     int R, int C, int src_ld, int dst_ld,
                                                     int Cpad,
                                                     size_t src_zstride, size_t dst_zstride,
                                                     int zmod,
                                                     size_t src_lstride, size_t dst_lstride) {
    __shared__ float tile[32][33];
    int z = blockIdx.z;
    int l = z / zmod, sub = z - l * zmod;
    src += (size_t)l * src_lstride + (size_t)sub * src_zstride;
    dst += (size_t)l * dst_lstride + (size_t)sub * dst_zstride;
    int tx = threadIdx.x & 31, ty = threadIdx.x >> 5;  // 32 x 8
    int r0 = blockIdx.y * 32, c0 = blockIdx.x * 32;
#pragma unroll
    for (int i = 0; i < 4; i++) {
        int r = r0 + ty + i * 8, c = c0 + tx;
        tile[ty + i * 8][tx] = (r < R && c < C) ? src[(size_t)r * src_ld + c] : 0.f;
    }
    __syncthreads();
#pragma unroll
    for (int i = 0; i < 4; i++) {
        int c = c0 + ty + i * 8, r = r0 + tx;
        if (c < Cpad && r < R) dst[(size_t)c * dst_ld + r] = f2bf(tile[tx][ty + i * 8]);
    }
}

// ---------------------------------------------------------------------------
// Pack QKV bias [768|768|768] -> qkvb[l][2304] for all 12 layers
// ---------------------------------------------------------------------------
__global__ void pack_qkv_bias(const float* __restrict__ bq, const float* __restrict__ bk,
                              const float* __restrict__ bv, float* __restrict__ qkvb) {
    int l = blockIdx.y;
    int j = blockIdx.x * 256 + threadIdx.x;
    if (j < 2304)
        qkvb[l * 2304 + j] =
            (j < 768) ? bq[l * 768 + j] : (j < 1536 ? bk[l * 768 + j - 768] : bv[l * 768 + j - 1536]);
}

// ---------------------------------------------------------------------------
// GEMM: C[M,N] = A[M,K](bf16,row-major) @ Bt[N,K](bf16,row-major)^T
// 128x128 tile, BK=32, 256 threads (4 waves, each 64x64 via 4x4 mfma 16x16x32).
// Grid: (x = M/128, y = N/128, z = KSPLIT). M-fastest + bijective XCD-chunk
// swizzle (all M-blocks of one B-panel co-resident on one XCD -> L2 reuse).
// 2-phase double-buffered main loop (T3-minimal).
// LDS bank-conflict fix (T2 / rule #21, both-sides XOR): global source chunk
// pre-swizzled ch = (li&3) ^ ((li>>3)&3) with a LINEAR global_load_lds dest;
// ds_read uses the same XOR (quad ^ ((ln15>>1)&3)) -> 2-way per 16-lane phase
// (free) instead of 8-way.
// EPI: 0 = store f32 (acc+bias)     [QKV, vocab]
//      2 = store bf16 (acc+bias)    [FFN1 -> t1]
//      4 = store f32 raw partial to outf + z*M*N  [split-K proj / FFN2]
// ---------------------------------------------------------------------------
template <int EPI>
__global__ __launch_bounds__(256) void gemm_bt(const u16* __restrict__ A,
                                               const u16* __restrict__ Bt,
                                               const float* __restrict__ bias,
                                               float* __restrict__ outf, u16* __restrict__ outb,
                                               int M, int N, int K) {
    __shared__ __align__(16) u16 As[2 * 128 * 32];
    __shared__ __align__(16) u16 Bs[2 * 128 * 32];
    const int t = threadIdx.x;
    const int lane = t & 63, wave = t >> 6;
    const int ln15 = lane & 15, quad = lane >> 4;
    const int chq = quad ^ ((ln15 >> 1) & 3);  // XOR-swizzled read chunk
    const int wm = (wave >> 1) * 64, wn = (wave & 1) * 64;

    // bijective XCD-chunk swizzle over (x,y); M (x) fastest
    int nwg = (int)(gridDim.x * gridDim.y);
    int bid = (int)(blockIdx.x + blockIdx.y * gridDim.x);
    int q = nwg >> 3, r = nwg & 7;
    int xcd = bid & 7, loc = bid >> 3;
    int swz = (xcd < r) ? xcd * (q + 1) + loc : r * (q + 1) + (xcd - r) * q + loc;
    long mb = swz % (int)gridDim.x;
    long nb = swz / (int)gridDim.x;
    const long m0 = mb * 128, n0 = nb * 128;

    const int KC = K / (int)gridDim.z;       // per-slice K
    const int kb0 = (int)blockIdx.z * KC;

    auto stage = [&](int buf, int kb) {
        u16* asb = As + buf * (128 * 32);
        u16* bsb = Bs + buf * (128 * 32);
#pragma unroll
        for (int i = 0; i < 2; i++) {
            int li = i * 256 + t;
            int row = li >> 2;
            int ch = (li & 3) ^ ((li >> 3) & 3);  // pre-swizzled source chunk
            const u16* ga = A + (m0 + row) * (long)K + kb + ch * 8;
            __builtin_amdgcn_global_load_lds(
                (const __attribute__((address_space(1))) u32*)ga,
                (__attribute__((address_space(3))) u32*)(asb + li * 8), 16, 0, 0);
            const u16* gb = Bt + (n0 + row) * (long)K + kb + ch * 8;
            __builtin_amdgcn_global_load_lds(
                (const __attribute__((address_space(1))) u32*)gb,
                (__attribute__((address_space(3))) u32*)(bsb + li * 8), 16, 0, 0);
        }
    };

    float4v acc[4][4];
#pragma unroll
    for (int i = 0; i < 4; i++)
#pragma unroll
        for (int j = 0; j < 4; j++) acc[i][j] = float4v{0.f, 0.f, 0.f, 0.f};

    stage(0, kb0);
    __syncthreads();
    int cur = 0;
    for (int kb = kb0; kb < kb0 + KC; kb += 32) {
        if (kb + 32 < kb0 + KC) stage(cur ^ 1, kb + 32);  // prefetch overlaps compute
        const u16* asb = As + cur * (128 * 32);
        const u16* bsb = Bs + cur * (128 * 32);
        short8 af[4], bfr[4];
#pragma unroll
        for (int ti = 0; ti < 4; ti++)
            af[ti] = *(const short8*)(asb + (wm + ti * 16 + ln15) * 32 + chq * 8);
#pragma unroll
        for (int tj = 0; tj < 4; tj++)
            bfr[tj] = *(const short8*)(bsb + (wn + tj * 16 + ln15) * 32 + chq * 8);
#pragma unroll
        for (int ti = 0; ti < 4; ti++)
#pragma unroll
            for (int tj = 0; tj < 4; tj++)
                acc[ti][tj] = __builtin_amdgcn_mfma_f32_16x16x32_bf16(af[ti], bfr[tj],
                                                                     acc[ti][tj], 0, 0, 0);
        __syncthreads();
        cur ^= 1;
    }

    if constexpr (EPI == 4) outf += (size_t)blockIdx.z * (size_t)M * N;

#pragma unroll
    for (int ti = 0; ti < 4; ti++) {
#pragma unroll
        for (int r2 = 0; r2 < 4; r2++) {
            long gm = m0 + wm + ti * 16 + quad * 4 + r2;
#pragma unroll
            for (int tj = 0; tj < 4; tj++) {
                long gn = n0 + wn + tj * 16 + ln15;
                if (gn < N) {
                    float v = acc[ti][tj][r2];
                    if constexpr (EPI != 4) v += bias[gn];
                    if constexpr (EPI == 2)
                        outb[gm * (long)N + gn] = f2bf(v);
                    else
                        outf[gm * (long)N + gn] = v;
                }
            }
        }
    }
}

// ---------------------------------------------------------------------------
// Attention: one block per (b,h). S=128, HD=64. f32 math.
// qkv layout: [t=b*128+s][2304] with cols 0..767=Q, 768..1535=K, 1536..2303=V
// writes o (concat heads) as bf16 [t][768]
// ---------------------------------------------------------------------------
__global__ __launch_bounds__(256) void attn_k(const float* __restrict__ qkv,
                                              const int* __restrict__ ignore,
                                              u16* __restrict__ obf) {
    const int bh = blockIdx.x;
    const int b = bh / 12, h = bh % 12;
    __shared__ float ks[128][65];
    __shared__ float vs[128][64];
    __shared__ float qrow[4][64];
    __shared__ float ps[4][128];
    __shared__ int ig[128];
    const int t = threadIdx.x;
    for (int i = t; i < 128 * 64; i += 256) {
        int s = i >> 6, e = i & 63;
        size_t base = ((size_t)(b * 128 + s)) * 2304 + h * 64 + e;
        ks[s][e] = qkv[base + 768];
        vs[s][e] = qkv[base + 1536];
    }
    if (t < 128) ig[t] = ignore[b * 128 + t];
    __syncthreads();
    const int wave = t >> 6, lane = t & 63;
    for (int r = wave; r < 128; r += 4) {
        qrow[wave][lane] = qkv[((size_t)(b * 128 + r)) * 2304 + h * 64 + lane];
        float s1 = 0.f, s2 = 0.f;
#pragma unroll 8
        for (int e = 0; e < 64; e++) {
            float qe = qrow[wave][e];
            s1 = fmaf(qe, ks[lane][e], s1);
            s2 = fmaf(qe, ks[lane + 64][e], s2);
        }
        s1 *= 0.125f;  // 1/sqrt(64)
        s2 *= 0.125f;
        int k1 = lane, k2 = lane + 64;
        bool ok1 = (k1 <= r) && (ig[k1] == 0 || k1 == r);
        bool ok2 = (k2 <= r) && (ig[k2] == 0 || k2 == r);
        if (!ok1) s1 = -3.0e38f;
        if (!ok2) s2 = -3.0e38f;
        float mx = fmaxf(s1, s2);
#pragma unroll
        for (int off = 32; off; off >>= 1) mx = fmaxf(mx, __shfl_xor(mx, off));
        float e1 = expf(s1 - mx), e2 = expf(s2 - mx);
        float sm = e1 + e2;
#pragma unroll
        for (int off = 32; off; off >>= 1) sm += __shfl_xor(sm, off);
        float inv = 1.f / sm;
        ps[wave][k1] = e1 * inv;
        ps[wave][k2] = e2 * inv;
        float o = 0.f;
#pragma unroll 8
        for (int kp = 0; kp < 128; kp++) o = fmaf(ps[wave][kp], vs[kp][lane], o);
        obf[((size_t)(b * 128 + r)) * 768 + h * 64 + lane] = f2bf(o);
    }
}

// ---------------------------------------------------------------------------
extern "C" void kernel_launch(void* const* d_in, const int* in_sizes, int n_in,
                              void* d_out, int out_size, void* d_ws, size_t ws_size,
                              hipStream_t stream) {
    const int* x     = (const int*)d_in[0];
    const int* ign   = (const int*)d_in[1];
    const float* bpe = (const float*)d_in[2];
    const float* pe  = (const float*)d_in[3];
    const float* Wq  = (const float*)d_in[4];
    const float* bq  = (const float*)d_in[5];
    const float* Wk  = (const float*)d_in[6];
    const float* bk  = (const float*)d_in[7];
    const float* Wv  = (const float*)d_in[8];
    const float* bv  = (const float*)d_in[9];
    const float* Wo  = (const float*)d_in[10];
    const float* bo  = (const float*)d_in[11];
    const float* W1  = (const float*)d_in[12];
    const float* b1  = (const float*)d_in[13];
    const float* W2  = (const float*)d_in[14];
    const float* b2  = (const float*)d_in[15];
    const float* ln1w = (const float*)d_in[16];
    const float* ln1b = (const float*)d_in[17];
    const float* ln2w = (const float*)d_in[18];
    const float* ln2b = (const float*)d_in[19];
    const float* Wout = (const float*)d_in[20];
    const float* bout = (const float*)d_in[21];
    float* out = (float*)d_out;

    // Hoisted path needs 275,558,400 B; fall back to per-layer staging if less.
    const bool hoist = ws_size >= 275558400ull;
    const int NL = hoist ? 12 : 1;

    char* p = (char*)d_ws;
    auto alloc = [&](size_t bytes) {
        char* r = p;
        p += (bytes + 255) & ~(size_t)255;
        return r;
    };
    float* hf   = (float*)alloc((size_t)2048 * 768 * 4);
    u16* hb     = (u16*)alloc((size_t)2048 * 768 * 2);
    float* qkv  = (float*)alloc((size_t)2048 * 2304 * 4);  // also: split-K partials
    u16* obf    = (u16*)alloc((size_t)2048 * 768 * 2);
    u16* t1b    = (u16*)alloc((size_t)2048 * 3072 * 2);
    u16* Wqkv_t = (u16*)alloc((size_t)NL * 2304 * 768 * 2);
    u16* Wo_t   = (u16*)alloc((size_t)NL * 768 * 768 * 2);
    u16* W1_t   = (u16*)alloc((size_t)NL * 3072 * 768 * 2);
    u16* W2_t   = (u16*)alloc((size_t)NL * 768 * 3072 * 2);
    u16* Wout_t = (u16*)alloc((size_t)40064 * 768 * 2);
    float* qkvb = (float*)alloc((size_t)12 * 2304 * 4);
    float* pf   = (float*)qkv;  // split-K partial buffer (proj: 2, FFN2: 3 slices)

    embed_k<<<2048, 256, 0, stream>>>(x, bpe, pe, hf, hb);
    pack_qkv_bias<<<dim3(9, 12), 256, 0, stream>>>(bq, bk, bv, qkvb);
    // vocab weight repack [768 x 40000] -> [40064 x 768] bf16
    transpose_cvt<<<dim3(1252, 24, 1), 256, 0, stream>>>(Wout, Wout_t, 768, 40000, 40000, 768,
                                                         40064, 0, 0, 1, 0, 0);
    if (hoist) {
        transpose_cvt<<<dim3(2, 24, 144), 256, 0, stream>>>(
            Wq, Wqkv_t, 768, 64, 64, 768, 64, (size_t)49152, (size_t)49152, 12,
            (size_t)589824, (size_t)1769472);
        transpose_cvt<<<dim3(2, 24, 144), 256, 0, stream>>>(
            Wk, Wqkv_t + 589824, 768, 64, 64, 768, 64, (size_t)49152, (size_t)49152, 12,
            (size_t)589824, (size_t)1769472);
        transpose_cvt<<<dim3(2, 24, 144), 256, 0, stream>>>(
            Wv, Wqkv_t + 1179648, 768, 64, 64, 768, 64, (size_t)49152, (size_t)49152, 12,
            (size_t)589824, (size_t)1769472);
        transpose_cvt<<<dim3(24, 24, 12), 256, 0, stream>>>(
            Wo, Wo_t, 768, 768, 768, 768, 768, 0, 0, 1, (size_t)589824, (size_t)589824);
        transpose_cvt<<<dim3(96, 24, 12), 256, 0, stream>>>(
            W1, W1_t, 768, 3072, 3072, 768, 3072, 0, 0, 1, (size_t)2359296, (size_t)2359296);
        transpose_cvt<<<dim3(24, 96, 12), 256, 0, stream>>>(
            W2, W2_t, 3072, 768, 768, 3072, 768, 0, 0, 1, (size_t)2359296, (size_t)2359296);
    }

    for (int l = 0; l < 12; l++) {
        const u16* WqkvL = Wqkv_t + (hoist ? (size_t)l * 1769472 : 0);
        const u16* WoL   = Wo_t   + (hoist ? (size_t)l * 589824 : 0);
        const u16* W1L   = W1_t   + (hoist ? (size_t)l * 2359296 : 0);
        const u16* W2L   = W2_t   + (hoist ? (size_t)l * 2359296 : 0);
        if (!hoist) {
            transpose_cvt<<<dim3(2, 24, 12), 256, 0, stream>>>(
                Wq + (size_t)l * 589824, Wqkv_t, 768, 64, 64, 768, 64,
                (size_t)49152, (size_t)49152, 12, 0, 0);
            transpose_cvt<<<dim3(2, 24, 12), 256, 0, stream>>>(
                Wk + (size_t)l * 589824, Wqkv_t + 589824, 768, 64, 64, 768, 64,
                (size_t)49152, (size_t)49152, 12, 0, 0);
            transpose_cvt<<<dim3(2, 24, 12), 256, 0, stream>>>(
                Wv + (size_t)l * 589824, Wqkv_t + 1179648, 768, 64, 64, 768, 64,
                (size_t)49152, (size_t)49152, 12, 0, 0);
            transpose_cvt<<<dim3(24, 24, 1), 256, 0, stream>>>(
                Wo + (size_t)l * 589824, Wo_t, 768, 768, 768, 768, 768, 0, 0, 1, 0, 0);
            transpose_cvt<<<dim3(96, 24, 1), 256, 0, stream>>>(
                W1 + (size_t)l * 2359296, W1_t, 768, 3072, 3072, 768, 3072, 0, 0, 1, 0, 0);
            transpose_cvt<<<dim3(24, 96, 1), 256, 0, stream>>>(
                W2 + (size_t)l * 2359296, W2_t, 3072, 768, 768, 3072, 768, 0, 0, 1, 0, 0);
        }
        // QKV GEMM -> qkv f32 [2048 x 2304]
        gemm_bt<0><<<dim3(16, 18, 1), 256, 0, stream>>>(hb, WqkvL, qkvb + l * 2304,
                                                        qkv, nullptr, 2048, 2304, 768);
        // attention -> obf bf16 [2048 x 768]
        attn_k<<<192, 256, 0, stream>>>(qkv, ign, obf);
        // out proj, split-K=2 -> partials in pf (qkv buffer is dead now)
        gemm_bt<4><<<dim3(16, 6, 2), 256, 0, stream>>>(obf, WoL, nullptr,
                                                       pf, nullptr, 2048, 768, 768);
        // fused: sum partials + bo + residual(hf) + LN1 -> hf, hb
        ln_fused_k<2, 0><<<2048, 256, 0, stream>>>(pf, bo + l * 768, hf,
                                                   ln1w + l * 768, ln1b + l * 768, hf, hb);
        // FFN1 -> t1 bf16 [2048 x 3072]
        gemm_bt<2><<<dim3(16, 24, 1), 256, 0, stream>>>(hb, W1L, b1 + l * 3072,
                                                        nullptr, t1b, 2048, 3072, 768);
        // FFN2, split-K=3 (K=3072 -> 3x1024) -> partials in pf
        gemm_bt<4><<<dim3(16, 6, 3), 256, 0, stream>>>(t1b, W2L, nullptr,
                                                       pf, nullptr, 2048, 768, 3072);
        // fused: sum partials + b2 + GELU + residual(hf) + LN2 -> hf, hb
        ln_fused_k<3, 1><<<2048, 256, 0, stream>>>(pf, b2 + l * 768, hf,
                                                   ln2w + l * 768, ln2b + l * 768, hf, hb);
    }

    // final vocab projection: out[2048 x 40000] f32 (swizzled, normal stores)
    gemm_bt<0><<<dim3(16, 313, 1), 256, 0, stream>>>(hb, Wout_t, bout,
                                                     out, nullptr, 2048, 40000, 768);
}